// Round 3
// baseline (528.143 us; speedup 1.0000x reference)
//
#include <hip/hip_runtime.h>
#include <hip/hip_bf16.h>
#include <math.h>

// ---------------------------------------------------------------------------
// ModelFC_49134425866355 on MI355X (gfx950)
//
// Pipeline:
//   prep:   E fp32 -> bf16 ; W1 -> W1t bf16 [1536][768] ; W2 -> W2t bf16 [128][1536] (pad rows 100..127 = 0)
//   gemm1:  act = bf16( gelu_exact( E@W1 + b1 ) )        [32768][1536]   (MFMA 16x16x32 bf16)
//   ln:     act = LN(act)*g + b  (in place, per row, eps=1e-12)
//   gemm2:  logits fp32 = act@W2 + b2                    [32768][100]
//   own:    exact fp32 recompute of the 512 "own" rows (rows 520a+j), split
//           into own_h (384 blk) / own_ln (512 blk) / own_logits (512 blk)
//           -- replaces the 64-block latency-bound own_rows (148 us, occ 5.7%)
//   final:  VG_scores / VG_index / sel from own_logits (fp32-exact argmax!)
//   scores: out[t*8+k] = logits[t, sel]  (t = l*512 + m*8 + j)
// ---------------------------------------------------------------------------

typedef __bf16 bf16_t;
typedef __bf16  bf16x8  __attribute__((ext_vector_type(8)));
typedef float   floatx4 __attribute__((ext_vector_type(4)));

__device__ __forceinline__ float gelu_exact(float x) {
    return 0.5f * x * (1.0f + erff(x * 0.7071067811865475f));
}

// async global->LDS, 16B per lane; lds base must be wave-uniform (HW adds lane*16)
__device__ __forceinline__ void gl_lds16(const bf16_t* g, bf16_t* l) {
    __builtin_amdgcn_global_load_lds(
        (const __attribute__((address_space(1))) void*)g,
        (__attribute__((address_space(3))) void*)l, 16, 0, 0);
}

// ---------------------------------------------------------------------------
// prep kernels
// ---------------------------------------------------------------------------
__global__ __launch_bounds__(256) void cvt_e(const float4* __restrict__ in,
                                             bf16_t* __restrict__ outp, int n4) {
    int t = blockIdx.x * 256 + threadIdx.x;
    if (t >= n4) return;
    float4 v = in[t];
    union { bf16_t h[4]; uint2 u; } u;
    u.h[0] = (bf16_t)v.x; u.h[1] = (bf16_t)v.y;
    u.h[2] = (bf16_t)v.z; u.h[3] = (bf16_t)v.w;
    *(uint2*)(outp + (size_t)t * 4) = u.u;
}

// W1 [768][1536] fp32 -> W1t [1536][768] bf16 (writes coalesced)
__global__ __launch_bounds__(256) void tr_w1(const float* __restrict__ W1,
                                             bf16_t* __restrict__ W1t) {
    int t = blockIdx.x * 256 + threadIdx.x;   // 1536*768 threads exactly
    int k = t % 768, n = t / 768;
    W1t[t] = (bf16_t)W1[(size_t)k * 1536 + n];
}

// W2 [1536][100] fp32 -> W2t [128][1536] bf16, pad rows n>=100 with zeros
__global__ __launch_bounds__(256) void tr_w2(const float* __restrict__ W2,
                                             bf16_t* __restrict__ W2t) {
    int t = blockIdx.x * 256 + threadIdx.x;   // 128*1536 threads exactly
    int k = t % 1536, n = t / 1536;
    W2t[t] = (n < 100) ? (bf16_t)W2[(size_t)k * 100 + n] : (bf16_t)0.0f;
}

// ---------------------------------------------------------------------------
// m97-style bf16 MFMA GEMM, A [M][K] bf16, Bt [N][K] bf16 (both K-contiguous).
// 128x128 block tile, BK=64, 4 waves each computing 64x64 via 4x4 MFMA tiles.
// XOR swizzle on 16B k-chunks (chunk ^= row&7) to break LDS bank aliasing;
// swizzle applied on the GLOBAL source so global_load_lds stays lane-contiguous.
// MODE 0: C = bf16(gelu(acc + bias[n])), stride N.  MODE 1: fp32 out, n<nout.
// ---------------------------------------------------------------------------
template<int MODE>
__global__ __launch_bounds__(256) void mfma_gemm_bt(
        const bf16_t* __restrict__ A, const bf16_t* __restrict__ Bt,
        const float* __restrict__ bias, void* __restrict__ Cout,
        int M, int N, int K, int nout) {
    __shared__ alignas(16) bf16_t sA[128 * 64];   // [row m][64 k], 16 KB
    __shared__ alignas(16) bf16_t sB[128 * 64];   // [row n][64 k], 16 KB

    const int tid  = threadIdx.x;
    const int lane = tid & 63;
    const int wave = tid >> 6;
    const int wr = wave >> 1, wc = wave & 1;     // 2x2 waves over 128x128
    const int m0 = blockIdx.y * 128;
    const int n0 = blockIdx.x * 128;
    const int q  = lane >> 4;                    // quad 0..3
    const int l15 = lane & 15;

    floatx4 acc[4][4] = {};

    const int nK = K >> 6;
    for (int kt = 0; kt < nK; ++kt) {
        const int k0 = kt * 64;
        __syncthreads();   // previous compute done before LDS overwrite
        #pragma unroll
        for (int c = 0; c < 4; ++c) {
            const int s    = c * 256 + tid;
            const int row  = s >> 3;             // 8 slots of 16B per 64-k row
            const int col  = s & 7;
            const int gcol = col ^ (row & 7);    // source-side swizzle
            gl_lds16(A  + (size_t)(m0 + row) * K + k0 + gcol * 8,
                     sA + (c * 256 + wave * 64) * 8);
            gl_lds16(Bt + (size_t)(n0 + row) * K + k0 + gcol * 8,
                     sB + (c * 256 + wave * 64) * 8);
        }
        __syncthreads();   // drains vmcnt(0) for global_load_lds, then barrier

        #pragma unroll
        for (int ks = 0; ks < 2; ++ks) {
            bf16x8 af[4], bfr[4];
            const int chunk = ((ks * 4 + q) ^ (lane & 7));  // row&7 == lane&7 here
            #pragma unroll
            for (int t4 = 0; t4 < 4; ++t4) {
                const int rA = wr * 64 + t4 * 16 + l15;
                const int rB = wc * 64 + t4 * 16 + l15;
                af[t4]  = *(const bf16x8*)(sA + rA * 64 + chunk * 8);
                bfr[t4] = *(const bf16x8*)(sB + rB * 64 + chunk * 8);
            }
            #pragma unroll
            for (int mt = 0; mt < 4; ++mt)
                #pragma unroll
                for (int nt = 0; nt < 4; ++nt)
                    acc[mt][nt] = __builtin_amdgcn_mfma_f32_16x16x32_bf16(
                        af[mt], bfr[nt], acc[mt][nt], 0, 0, 0);
        }
    }

    // epilogue: C/D layout col = lane&15, row = (lane>>4)*4 + r  [m89 verified]
    #pragma unroll
    for (int mt = 0; mt < 4; ++mt) {
        #pragma unroll
        for (int nt = 0; nt < 4; ++nt) {
            const int n = n0 + wc * 64 + nt * 16 + l15;
            const float bv = (n < nout) ? bias[n] : 0.0f;
            #pragma unroll
            for (int r = 0; r < 4; ++r) {
                const int m = m0 + wr * 64 + mt * 16 + q * 4 + r;
                const float v = acc[mt][nt][r] + bv;
                if (MODE == 0) {
                    ((bf16_t*)Cout)[(size_t)m * N + n] = (bf16_t)gelu_exact(v);
                } else {
                    if (n < nout) ((float*)Cout)[(size_t)m * nout + n] = v;
                }
            }
        }
    }
}

// ---------------------------------------------------------------------------
// per-row LayerNorm in place over act bf16 [32768][1536], eps = 1e-12.
// 192 threads/row, one bf16x8 (16B) load + store per thread, shuffle reduce.
// ---------------------------------------------------------------------------
__global__ __launch_bounds__(192) void ln_rows(bf16_t* __restrict__ act,
                                               const float* __restrict__ lng,
                                               const float* __restrict__ lnb) {
    const int row = blockIdx.x, tid = threadIdx.x;
    const int lane = tid & 63, wave = tid >> 6;   // 3 waves
    bf16_t* p = act + (size_t)row * 1536 + tid * 8;   // rows 16B-aligned (3072B stride)
    bf16x8 v = *(const bf16x8*)p;
    float x[8];
    #pragma unroll
    for (int i = 0; i < 8; ++i) x[i] = (float)v[i];

    __shared__ float red[8];
    float s = 0.f;
    #pragma unroll
    for (int i = 0; i < 8; ++i) s += x[i];
    #pragma unroll
    for (int o = 32; o > 0; o >>= 1) s += __shfl_xor(s, o, 64);
    if (lane == 0) red[wave] = s;
    __syncthreads();
    const float mu = (red[0] + red[1] + red[2]) * (1.0f / 1536.0f);

    float s2 = 0.f;
    #pragma unroll
    for (int i = 0; i < 8; ++i) { float d = x[i] - mu; s2 += d * d; }
    #pragma unroll
    for (int o = 32; o > 0; o >>= 1) s2 += __shfl_xor(s2, o, 64);
    if (lane == 0) red[4 + wave] = s2;   // different slots: no extra barrier
    __syncthreads();
    const float rstd = rsqrtf((red[4] + red[5] + red[6]) * (1.0f / 1536.0f) + 1e-12f);

    const float4 g0 = *(const float4*)(lng + tid * 8);
    const float4 g1 = *(const float4*)(lng + tid * 8 + 4);
    const float4 b0 = *(const float4*)(lnb + tid * 8);
    const float4 b1 = *(const float4*)(lnb + tid * 8 + 4);
    const float gg[8] = {g0.x, g0.y, g0.z, g0.w, g1.x, g1.y, g1.z, g1.w};
    const float bb[8] = {b0.x, b0.y, b0.z, b0.w, b1.x, b1.y, b1.z, b1.w};
    bf16x8 o;
    #pragma unroll
    for (int i = 0; i < 8; ++i) o[i] = (bf16_t)((x[i] - mu) * rstd * gg[i] + bb[i]);
    *(bf16x8*)p = o;
}

// ---------------------------------------------------------------------------
// exact fp32 own-row path, part 1: hbuf[512][1536] = gelu(E_own @ W1 + b1).
// Block (a, cc): rows 520a..520a+7, cols cc*256..cc*256+255. E-row reads are
// wave-uniform (scalar loads); W1 reads coalesced; 8 FMA per W1 load.
// ---------------------------------------------------------------------------
__global__ __launch_bounds__(256) void own_h(
        const float* __restrict__ E, const float* __restrict__ W1,
        const float* __restrict__ b1, float* __restrict__ hbuf) {
    const int a   = blockIdx.x;                  // 0..63
    const int col = blockIdx.y * 256 + threadIdx.x;
    const float* Erow = E + (size_t)(520 * a) * 768;
    float acc[8] = {};
    for (int k = 0; k < 768; ++k) {
        const float w = W1[(size_t)k * 1536 + col];
        #pragma unroll
        for (int j = 0; j < 8; ++j) acc[j] += w * Erow[(size_t)j * 768 + k];
    }
    const float bv = b1[col];
    #pragma unroll
    for (int j = 0; j < 8; ++j)
        hbuf[(size_t)(a * 8 + j) * 1536 + col] = gelu_exact(acc[j] + bv);
}

// part 2: in-place fp32 LayerNorm of hbuf rows (512 blocks, 256 thr, shuffle)
__global__ __launch_bounds__(256) void own_ln(float* __restrict__ hbuf,
                                              const float* __restrict__ lng,
                                              const float* __restrict__ lnb) {
    const int row = blockIdx.x, tid = threadIdx.x;
    const int lane = tid & 63, wave = tid >> 6;   // 4 waves
    float* p = hbuf + (size_t)row * 1536;
    float x[6];
    #pragma unroll
    for (int i = 0; i < 6; ++i) x[i] = p[tid + i * 256];

    __shared__ float red[8];
    float s = 0.f;
    #pragma unroll
    for (int i = 0; i < 6; ++i) s += x[i];
    #pragma unroll
    for (int o = 32; o > 0; o >>= 1) s += __shfl_xor(s, o, 64);
    if (lane == 0) red[wave] = s;
    __syncthreads();
    const float mu = (red[0] + red[1] + red[2] + red[3]) * (1.0f / 1536.0f);

    float s2 = 0.f;
    #pragma unroll
    for (int i = 0; i < 6; ++i) { float d = x[i] - mu; s2 += d * d; }
    #pragma unroll
    for (int o = 32; o > 0; o >>= 1) s2 += __shfl_xor(s2, o, 64);
    if (lane == 0) red[4 + wave] = s2;
    __syncthreads();
    const float rstd = rsqrtf((red[4] + red[5] + red[6] + red[7]) * (1.0f / 1536.0f) + 1e-12f);

    #pragma unroll
    for (int i = 0; i < 6; ++i) {
        const int c = tid + i * 256;
        p[c] = (x[i] - mu) * rstd * lng[c] + lnb[c];
    }
}

// part 3: own[512][100] = hbuf @ W2 + b2 (one row per block; hbuf reads are
// wave-uniform scalar loads, W2 reads coalesced across d)
__global__ __launch_bounds__(128) void own_logits(
        const float* __restrict__ hbuf, const float* __restrict__ W2,
        const float* __restrict__ b2, float* __restrict__ own) {
    const int row = blockIdx.x;
    const int d = threadIdx.x;
    if (d >= 100) return;
    const float* hr = hbuf + (size_t)row * 1536;
    float acc = b2[d];
    for (int k = 0; k < 1536; ++k)
        acc += hr[k] * W2[(size_t)k * 100 + d];
    own[(size_t)row * 100 + d] = acc;
}

// ---------------------------------------------------------------------------
// VG_scores (max softmax = 1/sum exp(x-max)), VG_index (first-max argmax), sel
// ---------------------------------------------------------------------------
__global__ __launch_bounds__(256) void finalize(const float* __restrict__ own,
                                                float* __restrict__ out,
                                                int* __restrict__ sel) {
    const int e = blockIdx.x * 256 + threadIdx.x;
    if (e >= 512) return;
    const float* r = own + (size_t)e * 100;
    float best = r[0]; int bi = 0;
    for (int i = 1; i < 100; ++i) {
        const float v = r[i];
        if (v > best) { best = v; bi = i; }       // strict > keeps first max
    }
    float s = 0.f;
    for (int i = 0; i < 100; ++i) s += expf(r[i] - best);
    out[262144 + e] = 1.0f / s;                   // VG_scores
    out[262656 + e] = (float)bi;                  // VG_scores_index (as fp32)
    if (e == 511) *sel = bi;
}

// scores[0,l,m,j,k] = logits[l*512+m*8+j, sel] ; out flat = t*8+k, t=l*512+m*8+j
__global__ __launch_bounds__(256) void scores_out(const float* __restrict__ logits,
                                                  const int* __restrict__ selp,
                                                  float* __restrict__ out) {
    const int t = blockIdx.x * 256 + threadIdx.x; // 32768 threads exactly
    const int sel = *selp;
    const float v = logits[(size_t)t * 100 + sel];
    const float4 f = make_float4(v, v, v, v);
    float4* o = (float4*)(out + (size_t)t * 8);
    o[0] = f; o[1] = f;
}

// ---------------------------------------------------------------------------
extern "C" void kernel_launch(void* const* d_in, const int* in_sizes, int n_in,
                              void* d_out, int out_size, void* d_ws, size_t ws_size,
                              hipStream_t stream) {
    const float* E   = (const float*)d_in[0];
    const float* W1  = (const float*)d_in[1];
    const float* b1  = (const float*)d_in[2];
    const float* lng = (const float*)d_in[3];
    const float* lnb = (const float*)d_in[4];
    const float* W2  = (const float*)d_in[5];
    const float* b2  = (const float*)d_in[6];
    float* out = (float*)d_out;

    char* w = (char*)d_ws;
    auto carve = [&](size_t bytes) {
        void* p = (void*)w;
        w += (bytes + 255) & ~(size_t)255;
        return p;
    };
    bf16_t* Ebf    = (bf16_t*)carve((size_t)25165824 * 2);     // 50.3 MB
    bf16_t* W1t    = (bf16_t*)carve((size_t)1536 * 768 * 2);   //  2.4 MB
    bf16_t* W2t    = (bf16_t*)carve((size_t)128 * 1536 * 2);   //  0.4 MB
    bf16_t* act    = (bf16_t*)carve((size_t)32768 * 1536 * 2); // 100.7 MB
    float*  logits = (float*)carve((size_t)32768 * 100 * 4);   // 13.1 MB
    float*  hbuf   = (float*)carve((size_t)512 * 1536 * 4);    //  3.1 MB
    float*  own    = (float*)carve((size_t)512 * 100 * 4);
    int*    sel    = (int*)carve(256);

    cvt_e<<<24576, 256, 0, stream>>>((const float4*)E, Ebf, 6291456);
    tr_w1<<<4608, 256, 0, stream>>>(W1, W1t);
    tr_w2<<<768, 256, 0, stream>>>(W2, W2t);

    // GEMM1: [32768,768] @ [768,1536] -> act (gelu, bf16)
    mfma_gemm_bt<0><<<dim3(12, 256), 256, 0, stream>>>(Ebf, W1t, b1, act,
                                                       32768, 1536, 768, 1536);
    ln_rows<<<32768, 192, 0, stream>>>(act, lng, lnb);
    // GEMM2: [32768,1536] @ [1536,100(pad 128)] -> logits fp32
    mfma_gemm_bt<1><<<dim3(1, 256), 256, 0, stream>>>(act, W2t, b2, logits,
                                                      32768, 128, 1536, 100);

    // exact fp32 own-row path (parallelized: 384 + 512 + 512 blocks)
    own_h<<<dim3(64, 6), 256, 0, stream>>>(E, W1, b1, hbuf);
    own_ln<<<512, 256, 0, stream>>>(hbuf, lng, lnb);
    own_logits<<<512, 128, 0, stream>>>(hbuf, W2, b2, own);

    finalize<<<2, 256, 0, stream>>>(own, out, sel);
    scores_out<<<128, 256, 0, stream>>>(logits, sel, out);
}

// Round 4
// 508.335 us; speedup vs baseline: 1.0390x; 1.0390x over previous
//
#include <hip/hip_runtime.h>
#include <hip/hip_bf16.h>
#include <math.h>

// ---------------------------------------------------------------------------
// ModelFC_49134425866355 on MI355X (gfx950)
//
// Pipeline:
//   prep:   E fp32 -> bf16 ; W1 -> W1t bf16 [1536][768] ; W2 -> W2t bf16 [128][1536]
//   gemm1:  act = bf16( gelu_fast( E@W1 + b1 ) )   [32768][1536]  (MFMA, XCD-swizzled)
//   ln:     act = LN(act)*g + b   (wave-per-row, no barriers)
//   gemm2:  logits fp32 += act@W2 (split-K x4, unsafeAtomicAdd into zeroed buf;
//           b2 folded into scores_out)
//   own:    exact fp32 recompute of the 512 "own" rows (rows 520a+j):
//           own_h (split-K x2, raw partials) -> own_ln (gelu+bias+sum+LN) ->
//           own_logits (in-block split-K). Feeds fp32-exact argmax.
//   final:  VG_scores / VG_index / sel ; scores: out[t*8+k] = logits[t,sel]+b2[sel]
// ---------------------------------------------------------------------------

typedef __bf16 bf16_t;
typedef __bf16  bf16x8  __attribute__((ext_vector_type(8)));
typedef float   floatx4 __attribute__((ext_vector_type(4)));

__device__ __forceinline__ float gelu_exact(float x) {
    return 0.5f * x * (1.0f + erff(x * 0.7071067811865475f));
}
// tanh-form gelu via sigmoid: x*sigma(1.59577*(x+0.044715x^3)); |err|<~1e-3,
// below bf16 rounding of the bulk path. Own path keeps gelu_exact.
__device__ __forceinline__ float gelu_fast(float x) {
    const float z = x * (1.0f + 0.044715f * x * x);
    return __fdividef(x, 1.0f + __expf(-1.5957691216f * z));
}

// async global->LDS, 16B per lane; lds base wave-uniform (HW adds lane*16)
__device__ __forceinline__ void gl_lds16(const bf16_t* g, bf16_t* l) {
    __builtin_amdgcn_global_load_lds(
        (const __attribute__((address_space(1))) void*)g,
        (__attribute__((address_space(3))) void*)l, 16, 0, 0);
}

// ---------------------------------------------------------------------------
// prep kernels
// ---------------------------------------------------------------------------
__global__ __launch_bounds__(256) void cvt_e(const float4* __restrict__ in,
                                             bf16_t* __restrict__ outp, int n4) {
    int t = blockIdx.x * 256 + threadIdx.x;
    if (t >= n4) return;
    float4 v = in[t];
    union { bf16_t h[4]; uint2 u; } u;
    u.h[0] = (bf16_t)v.x; u.h[1] = (bf16_t)v.y;
    u.h[2] = (bf16_t)v.z; u.h[3] = (bf16_t)v.w;
    *(uint2*)(outp + (size_t)t * 4) = u.u;
}

__global__ __launch_bounds__(256) void tr_w1(const float* __restrict__ W1,
                                             bf16_t* __restrict__ W1t) {
    int t = blockIdx.x * 256 + threadIdx.x;   // 1536*768 threads exactly
    int k = t % 768, n = t / 768;
    W1t[t] = (bf16_t)W1[(size_t)k * 1536 + n];
}

__global__ __launch_bounds__(256) void tr_w2(const float* __restrict__ W2,
                                             bf16_t* __restrict__ W2t) {
    int t = blockIdx.x * 256 + threadIdx.x;   // 128*1536 threads exactly
    int k = t % 1536, n = t / 1536;
    W2t[t] = (n < 100) ? (bf16_t)W2[(size_t)k * 100 + n] : (bf16_t)0.0f;
}

// ---------------------------------------------------------------------------
// bf16 MFMA GEMM, A [M][K], Bt [N][K]. 128x128 tile, BK=64, K-range by
// blockIdx.z (ktz k-tiles per z-slice). SWIZ=1: XCD-aware remap so the 12
// n-tiles of one m-tile land on one XCD (A-tile + W1t resident in its L2).
// MODE 0: C = bf16(gelu_fast(acc + bias[n])), stride N.
// MODE 1: unsafeAtomicAdd fp32 into Cout[m*nout+n] (n<nout), no bias.
// ---------------------------------------------------------------------------
template<int MODE, int SWIZ>
__global__ __launch_bounds__(256) void mfma_gemm_bt(
        const bf16_t* __restrict__ A, const bf16_t* __restrict__ Bt,
        const float* __restrict__ bias, void* __restrict__ Cout,
        int M, int N, int K, int nout, int ktz) {
    __shared__ alignas(16) bf16_t sA[128 * 64];   // 16 KB
    __shared__ alignas(16) bf16_t sB[128 * 64];   // 16 KB

    int bx = blockIdx.x, by = blockIdx.y;
    if (SWIZ) {
        const int linear = blockIdx.x + gridDim.x * blockIdx.y;
        const int xcd  = linear & 7;
        const int slot = linear >> 3;
        bx = slot % gridDim.x;
        by = (slot / gridDim.x) * 8 + xcd;
    }
    const int tid  = threadIdx.x;
    const int lane = tid & 63;
    const int wave = tid >> 6;
    const int wr = wave >> 1, wc = wave & 1;
    const int m0 = by * 128;
    const int n0 = bx * 128;
    const int q  = lane >> 4;
    const int l15 = lane & 15;

    floatx4 acc[4][4] = {};

    const int ktb = blockIdx.z * ktz;
    for (int kt = ktb; kt < ktb + ktz; ++kt) {
        const int k0 = kt * 64;
        __syncthreads();
        #pragma unroll
        for (int c = 0; c < 4; ++c) {
            const int s    = c * 256 + tid;
            const int row  = s >> 3;
            const int col  = s & 7;
            const int gcol = col ^ (row & 7);    // source-side swizzle
            gl_lds16(A  + (size_t)(m0 + row) * K + k0 + gcol * 8,
                     sA + (c * 256 + wave * 64) * 8);
            gl_lds16(Bt + (size_t)(n0 + row) * K + k0 + gcol * 8,
                     sB + (c * 256 + wave * 64) * 8);
        }
        __syncthreads();

        #pragma unroll
        for (int ks = 0; ks < 2; ++ks) {
            bf16x8 af[4], bfr[4];
            const int chunk = ((ks * 4 + q) ^ (lane & 7));
            #pragma unroll
            for (int t4 = 0; t4 < 4; ++t4) {
                const int rA = wr * 64 + t4 * 16 + l15;
                const int rB = wc * 64 + t4 * 16 + l15;
                af[t4]  = *(const bf16x8*)(sA + rA * 64 + chunk * 8);
                bfr[t4] = *(const bf16x8*)(sB + rB * 64 + chunk * 8);
            }
            #pragma unroll
            for (int mt = 0; mt < 4; ++mt)
                #pragma unroll
                for (int nt = 0; nt < 4; ++nt)
                    acc[mt][nt] = __builtin_amdgcn_mfma_f32_16x16x32_bf16(
                        af[mt], bfr[nt], acc[mt][nt], 0, 0, 0);
        }
    }

    // epilogue: C/D layout col = lane&15, row = (lane>>4)*4 + r
    #pragma unroll
    for (int mt = 0; mt < 4; ++mt) {
        #pragma unroll
        for (int nt = 0; nt < 4; ++nt) {
            const int n = n0 + wc * 64 + nt * 16 + l15;
            const float bv = (MODE == 0) ? bias[n] : 0.0f;
            #pragma unroll
            for (int r = 0; r < 4; ++r) {
                const int m = m0 + wr * 64 + mt * 16 + q * 4 + r;
                const float v = acc[mt][nt][r] + bv;
                if (MODE == 0) {
                    ((bf16_t*)Cout)[(size_t)m * N + n] = (bf16_t)gelu_fast(v);
                } else {
                    if (n < nout)
                        unsafeAtomicAdd((float*)Cout + (size_t)m * nout + n, v);
                }
            }
        }
    }
}

// ---------------------------------------------------------------------------
// LayerNorm in place, ONE WAVE PER ROW (4 rows / 256-thr block). No LDS, no
// __syncthreads — pure shuffle reduction. 24 elems (3x bf16x8) per lane.
// ---------------------------------------------------------------------------
__global__ __launch_bounds__(256) void ln_rows(bf16_t* __restrict__ act,
                                               const float* __restrict__ lng,
                                               const float* __restrict__ lnb) {
    const int lane = threadIdx.x & 63, wv = threadIdx.x >> 6;
    const int row  = blockIdx.x * 4 + wv;
    bf16_t* p = act + (size_t)row * 1536 + lane * 8;
    bf16x8 v[3];
    #pragma unroll
    for (int s = 0; s < 3; ++s) v[s] = *(const bf16x8*)(p + s * 512);
    float x[24];
    #pragma unroll
    for (int s = 0; s < 3; ++s)
        #pragma unroll
        for (int i = 0; i < 8; ++i) x[s * 8 + i] = (float)v[s][i];

    float sum = 0.f;
    #pragma unroll
    for (int i = 0; i < 24; ++i) sum += x[i];
    #pragma unroll
    for (int o = 32; o > 0; o >>= 1) sum += __shfl_xor(sum, o, 64);
    const float mu = sum * (1.0f / 1536.0f);

    float s2 = 0.f;
    #pragma unroll
    for (int i = 0; i < 24; ++i) { float d = x[i] - mu; s2 += d * d; }
    #pragma unroll
    for (int o = 32; o > 0; o >>= 1) s2 += __shfl_xor(s2, o, 64);
    const float rstd = rsqrtf(s2 * (1.0f / 1536.0f) + 1e-12f);

    #pragma unroll
    for (int s = 0; s < 3; ++s) {
        const float4 g0 = *(const float4*)(lng + s * 512 + lane * 8);
        const float4 g1 = *(const float4*)(lng + s * 512 + lane * 8 + 4);
        const float4 b0 = *(const float4*)(lnb + s * 512 + lane * 8);
        const float4 b1 = *(const float4*)(lnb + s * 512 + lane * 8 + 4);
        const float gg[8] = {g0.x, g0.y, g0.z, g0.w, g1.x, g1.y, g1.z, g1.w};
        const float bb[8] = {b0.x, b0.y, b0.z, b0.w, b1.x, b1.y, b1.z, b1.w};
        bf16x8 o;
        #pragma unroll
        for (int i = 0; i < 8; ++i)
            o[i] = (bf16_t)((x[s * 8 + i] - mu) * rstd * gg[i] + bb[i]);
        *(bf16x8*)(p + s * 512) = o;
    }
}

// ---------------------------------------------------------------------------
// own path part 1: raw partial sums hpart[kh][512][1536] = E_own @ W1 (K-half
// kh). grid (64, 6, 2) = 768 blocks. No gelu/bias here (added in own_ln).
// ---------------------------------------------------------------------------
__global__ __launch_bounds__(256) void own_h(
        const float* __restrict__ E, const float* __restrict__ W1,
        float* __restrict__ hpart) {
    const int a   = blockIdx.x;
    const int col = blockIdx.y * 256 + threadIdx.x;
    const int kh  = blockIdx.z;
    const float* Erow = E + (size_t)(520 * a) * 768 + kh * 384;
    float acc[8] = {};
    for (int k = 0; k < 384; ++k) {
        const float w = W1[(size_t)(kh * 384 + k) * 1536 + col];
        #pragma unroll
        for (int j = 0; j < 8; ++j) acc[j] += w * Erow[(size_t)j * 768 + k];
    }
    #pragma unroll
    for (int j = 0; j < 8; ++j)
        hpart[(size_t)(kh * 512 + a * 8 + j) * 1536 + col] = acc[j];
}

// part 2: h = gelu_exact(p0+p1+b1), then fp32 LN -> hbuf (512 blocks)
__global__ __launch_bounds__(256) void own_ln(const float* __restrict__ hpart,
                                              const float* __restrict__ b1,
                                              const float* __restrict__ lng,
                                              const float* __restrict__ lnb,
                                              float* __restrict__ hbuf) {
    const int row = blockIdx.x, tid = threadIdx.x;
    const int lane = tid & 63, wv = tid >> 6;
    float x[6];
    #pragma unroll
    for (int i = 0; i < 6; ++i) {
        const int c = tid + i * 256;
        x[i] = gelu_exact(hpart[(size_t)row * 1536 + c]
                        + hpart[(size_t)(512 + row) * 1536 + c] + b1[c]);
    }
    __shared__ float red[8];
    float s = 0.f;
    #pragma unroll
    for (int i = 0; i < 6; ++i) s += x[i];
    #pragma unroll
    for (int o = 32; o > 0; o >>= 1) s += __shfl_xor(s, o, 64);
    if (lane == 0) red[wv] = s;
    __syncthreads();
    const float mu = (red[0] + red[1] + red[2] + red[3]) * (1.0f / 1536.0f);

    float s2 = 0.f;
    #pragma unroll
    for (int i = 0; i < 6; ++i) { float d = x[i] - mu; s2 += d * d; }
    #pragma unroll
    for (int o = 32; o > 0; o >>= 1) s2 += __shfl_xor(s2, o, 64);
    if (lane == 0) red[4 + wv] = s2;
    __syncthreads();
    const float rstd = rsqrtf((red[4] + red[5] + red[6] + red[7]) * (1.0f / 1536.0f) + 1e-12f);

    #pragma unroll
    for (int i = 0; i < 6; ++i) {
        const int c = tid + i * 256;
        hbuf[(size_t)row * 1536 + c] = (x[i] - mu) * rstd * lng[c] + lnb[c];
    }
}

// part 3: own[512][100] = hbuf @ W2 + b2, in-block K-split (d, ks) = (128, 2)
__global__ __launch_bounds__(256) void own_logits(
        const float* __restrict__ hbuf, const float* __restrict__ W2,
        const float* __restrict__ b2, float* __restrict__ own) {
    const int row = blockIdx.x;
    const int d  = threadIdx.x & 127;
    const int ks = threadIdx.x >> 7;
    const int dd = d < 100 ? d : 99;          // keep OOB lanes in-bounds
    const float* hr = hbuf + (size_t)row * 1536 + ks * 768;
    float acc = ks ? 0.0f : b2[dd];
    for (int k = 0; k < 768; ++k)
        acc += hr[k] * W2[(size_t)(ks * 768 + k) * 100 + dd];
    __shared__ float red[128];
    if (ks) red[d] = acc;
    __syncthreads();
    if (!ks && d < 100) own[(size_t)row * 100 + d] = acc + red[d];
}

// ---------------------------------------------------------------------------
__global__ __launch_bounds__(256) void finalize(const float* __restrict__ own,
                                                float* __restrict__ out,
                                                int* __restrict__ sel) {
    const int e = blockIdx.x * 256 + threadIdx.x;
    if (e >= 512) return;
    const float* r = own + (size_t)e * 100;
    float best = r[0]; int bi = 0;
    for (int i = 1; i < 100; ++i) {
        const float v = r[i];
        if (v > best) { best = v; bi = i; }       // strict > keeps first max
    }
    float s = 0.f;
    for (int i = 0; i < 100; ++i) s += expf(r[i] - best);
    out[262144 + e] = 1.0f / s;                   // VG_scores
    out[262656 + e] = (float)bi;                  // VG_scores_index
    if (e == 511) *sel = bi;
}

// out[t*8+k] = logits[t,sel] + b2[sel]   (bias folded here; logits are raw sums)
__global__ __launch_bounds__(256) void scores_out(const float* __restrict__ logits,
                                                  const float* __restrict__ b2,
                                                  const int* __restrict__ selp,
                                                  float* __restrict__ out) {
    const int t = blockIdx.x * 256 + threadIdx.x; // 32768 threads exactly
    const int sel = *selp;
    const float v = logits[(size_t)t * 100 + sel] + b2[sel];
    const float4 f = make_float4(v, v, v, v);
    float4* o = (float4*)(out + (size_t)t * 8);
    o[0] = f; o[1] = f;
}

// ---------------------------------------------------------------------------
extern "C" void kernel_launch(void* const* d_in, const int* in_sizes, int n_in,
                              void* d_out, int out_size, void* d_ws, size_t ws_size,
                              hipStream_t stream) {
    const float* E   = (const float*)d_in[0];
    const float* W1  = (const float*)d_in[1];
    const float* b1  = (const float*)d_in[2];
    const float* lng = (const float*)d_in[3];
    const float* lnb = (const float*)d_in[4];
    const float* W2  = (const float*)d_in[5];
    const float* b2  = (const float*)d_in[6];
    float* out = (float*)d_out;

    char* w = (char*)d_ws;
    auto carve = [&](size_t bytes) {
        void* p = (void*)w;
        w += (bytes + 255) & ~(size_t)255;
        return p;
    };
    bf16_t* Ebf    = (bf16_t*)carve((size_t)25165824 * 2);     // 50.3 MB
    bf16_t* W1t    = (bf16_t*)carve((size_t)1536 * 768 * 2);   //  2.4 MB
    bf16_t* W2t    = (bf16_t*)carve((size_t)128 * 1536 * 2);   //  0.4 MB
    bf16_t* act    = (bf16_t*)carve((size_t)32768 * 1536 * 2); // 100.7 MB
    float*  logits = (float*)carve((size_t)32768 * 100 * 4);   // 13.1 MB
    float*  own    = (float*)carve((size_t)512 * 100 * 4);
    int*    sel    = (int*)carve(256);
    // own-path scratch aliases Ebf (Ebf dead after gemm1; own_h runs later)
    float*  hpart  = (float*)Ebf;                          // 2*512*1536*4 = 6.3 MB
    float*  hbuf   = (float*)((char*)Ebf + (size_t)2 * 512 * 1536 * 4); // 3.1 MB

    cvt_e<<<24576, 256, 0, stream>>>((const float4*)E, Ebf, 6291456);
    tr_w1<<<4608, 256, 0, stream>>>(W1, W1t);
    tr_w2<<<768, 256, 0, stream>>>(W2, W2t);

    // GEMM1: [32768,768] @ [768,1536] -> act (gelu_fast, bf16), XCD-swizzled
    mfma_gemm_bt<0, 1><<<dim3(12, 256), 256, 0, stream>>>(
        Ebf, W1t, b1, act, 32768, 1536, 768, 1536, 12);
    ln_rows<<<8192, 256, 0, stream>>>(act, lng, lnb);

    // GEMM2: split-K x4, atomic accumulate into zeroed logits
    hipMemsetAsync(logits, 0, (size_t)32768 * 100 * 4, stream);
    mfma_gemm_bt<1, 0><<<dim3(1, 256, 4), 256, 0, stream>>>(
        act, W2t, nullptr, logits, 32768, 128, 1536, 100, 6);

    // exact fp32 own-row path
    own_h<<<dim3(64, 6, 2), 256, 0, stream>>>(E, W1, hpart);
    own_ln<<<512, 256, 0, stream>>>(hpart, b1, lng, lnb, hbuf);
    own_logits<<<512, 256, 0, stream>>>(hbuf, W2, b2, own);

    finalize<<<2, 256, 0, stream>>>(own, out, sel);
    scores_out<<<128, 256, 0, stream>>>(logits, b2, sel, out);
}

// Round 6
// 385.198 us; speedup vs baseline: 1.3711x; 1.3197x over previous
//
#include <hip/hip_runtime.h>
#include <hip/hip_bf16.h>
#include <math.h>

// ---------------------------------------------------------------------------
// ModelFC_49134425866355 on MI355X (gfx950)
//
// Key insight: logits[32768][100] feeds ONLY scores_out, which reads column
// `sel`. sel comes from the exact-fp32 own-row path (independent of the bulk
// pipeline). So there is NO bulk GEMM2: gather w2col = W2[:,sel] (6 KB) and
// fuse LayerNorm + GEMV into one wave-per-row pass over the gelu activations.
//
// Pipeline:
//   prep:   E fp32 -> bf16 ; W1 -> W1t bf16 [1536][768]
//   gemm1:  act = bf16( gelu_fast( E@W1 + b1 ) )  [32768][1536]
//           (MFMA 16x16x32; staging uses gl_lds16 with offset=0 — the only
//            HW-verified form; round-5's nonzero offset-immediate experiment
//            produced garbage and is reverted. Swizzle/addresses hoisted.)
//   own:    exact fp32 recompute of the 512 "own" rows (rows 520a+j):
//           own_h -> own_ln -> own_logits -> finalize (argmax/softmax/sel)
//   gather: w2col[k] = W2[k*100+sel], bsel = b2[sel]
//   lngemv: out[t*8+k] = dot(LN(act[t]), w2col) + bsel   (wave per row)
// ---------------------------------------------------------------------------

typedef __bf16 bf16_t;
typedef __bf16  bf16x8  __attribute__((ext_vector_type(8)));
typedef float   floatx4 __attribute__((ext_vector_type(4)));

__device__ __forceinline__ float gelu_exact(float x) {
    return 0.5f * x * (1.0f + erff(x * 0.7071067811865475f));
}
// tanh-form gelu via sigmoid; |err|<~1e-3, below bf16 rounding of bulk path.
__device__ __forceinline__ float gelu_fast(float x) {
    const float z = x * (1.0f + 0.044715f * x * x);
    return __fdividef(x, 1.0f + __expf(-1.5957691216f * z));
}

// async global->LDS, 16B per lane; lds base wave-uniform (HW adds lane*16).
// OFFSET ARG STAYS 0 — nonzero immediate is unverified and broke round 5.
__device__ __forceinline__ void gl_lds16(const bf16_t* g, bf16_t* l) {
    __builtin_amdgcn_global_load_lds(
        (const __attribute__((address_space(1))) void*)g,
        (__attribute__((address_space(3))) void*)l, 16, 0, 0);
}

// ---------------------------------------------------------------------------
// prep kernels
// ---------------------------------------------------------------------------
__global__ __launch_bounds__(256) void cvt_e(const float4* __restrict__ in,
                                             bf16_t* __restrict__ outp, int n4) {
    int t = blockIdx.x * 256 + threadIdx.x;
    if (t >= n4) return;
    float4 v = in[t];
    union { bf16_t h[4]; uint2 u; } u;
    u.h[0] = (bf16_t)v.x; u.h[1] = (bf16_t)v.y;
    u.h[2] = (bf16_t)v.z; u.h[3] = (bf16_t)v.w;
    *(uint2*)(outp + (size_t)t * 4) = u.u;
}

__global__ __launch_bounds__(256) void tr_w1(const float* __restrict__ W1,
                                             bf16_t* __restrict__ W1t) {
    int t = blockIdx.x * 256 + threadIdx.x;   // 1536*768 threads exactly
    int k = t % 768, n = t / 768;
    W1t[t] = (bf16_t)W1[(size_t)k * 1536 + n];
}

// ---------------------------------------------------------------------------
// GEMM1: [32768,768] @ [768,1536]^T-stored, 128x128 tile, BK=64, 12 K-tiles.
// Staging/read addresses hoisted out of the K-loop; K-advance via pointer
// arithmetic (known-good semantics).
// ---------------------------------------------------------------------------
__global__ __launch_bounds__(256) void gemm1(
        const bf16_t* __restrict__ A, const bf16_t* __restrict__ Bt,
        const float* __restrict__ bias, bf16_t* __restrict__ C) {
    constexpr int K = 768, N = 1536;
    __shared__ alignas(16) bf16_t sA[128 * 64];   // 16 KB
    __shared__ alignas(16) bf16_t sB[128 * 64];   // 16 KB

    // XCD-aware remap: 12 n-tiles of one m-tile land on one XCD
    const int linear = blockIdx.x + gridDim.x * blockIdx.y;
    const int xcd  = linear & 7;
    const int slot = linear >> 3;
    const int bx = slot % gridDim.x;
    const int by = (slot / gridDim.x) * 8 + xcd;

    const int tid  = threadIdx.x;
    const int lane = tid & 63;
    const int wave = tid >> 6;
    const int wr = wave >> 1, wc = wave & 1;
    const int m0 = by * 128;
    const int n0 = bx * 128;
    const int q  = lane >> 4;
    const int l15 = lane & 15;

    // staging bases (computed once; swizzle gcol = col ^ (row&7) on source)
    const bf16_t* gA[4]; const bf16_t* gB[4];
    bf16_t* lA[4]; bf16_t* lB[4];
    #pragma unroll
    for (int c = 0; c < 4; ++c) {
        const int s    = c * 256 + tid;
        const int row  = s >> 3;             // 8 slots of 16B per 64-k row
        const int col  = s & 7;
        const int gcol = col ^ (row & 7);    // source-side swizzle
        gA[c] = A  + (size_t)(m0 + row) * K + gcol * 8;
        gB[c] = Bt + (size_t)(n0 + row) * K + gcol * 8;
        lA[c] = sA + (c * 256 + wave * 64) * 8;   // wave-uniform base
        lB[c] = sB + (c * 256 + wave * 64) * 8;
    }
    // LDS read bases (fixed across K-steps)
    const bf16_t* rA[4]; const bf16_t* rB[4];
    #pragma unroll
    for (int t4 = 0; t4 < 4; ++t4) {
        rA[t4] = sA + (wr * 64 + t4 * 16 + l15) * 64;
        rB[t4] = sB + (wc * 64 + t4 * 16 + l15) * 64;
    }
    const int c0 = ((q)     ^ (lane & 7)) * 8;   // rA row & 7 == lane & 7
    const int c1 = ((4 + q) ^ (lane & 7)) * 8;

    floatx4 acc[4][4] = {};

    #pragma unroll
    for (int kt = 0; kt < 12; ++kt) {
        const int k0 = kt * 64;
        __syncthreads();   // prev compute done before LDS overwrite
        #pragma unroll
        for (int c = 0; c < 4; ++c) {
            gl_lds16(gA[c] + k0, lA[c]);
            gl_lds16(gB[c] + k0, lB[c]);
        }
        __syncthreads();   // drain vmcnt then barrier

        #pragma unroll
        for (int ks = 0; ks < 2; ++ks) {
            const int co = ks ? c1 : c0;
            bf16x8 af[4], bfr[4];
            #pragma unroll
            for (int t4 = 0; t4 < 4; ++t4) {
                af[t4]  = *(const bf16x8*)(rA[t4] + co);
                bfr[t4] = *(const bf16x8*)(rB[t4] + co);
            }
            #pragma unroll
            for (int mt = 0; mt < 4; ++mt)
                #pragma unroll
                for (int nt = 0; nt < 4; ++nt)
                    acc[mt][nt] = __builtin_amdgcn_mfma_f32_16x16x32_bf16(
                        af[mt], bfr[nt], acc[mt][nt], 0, 0, 0);
        }
    }

    // epilogue: C/D layout col = lane&15, row = (lane>>4)*4 + r
    #pragma unroll
    for (int mt = 0; mt < 4; ++mt) {
        #pragma unroll
        for (int nt = 0; nt < 4; ++nt) {
            const int n = n0 + wc * 64 + nt * 16 + l15;
            const float bv = bias[n];
            #pragma unroll
            for (int r = 0; r < 4; ++r) {
                const int m = m0 + wr * 64 + mt * 16 + q * 4 + r;
                C[(size_t)m * N + n] = (bf16_t)gelu_fast(acc[mt][nt][r] + bv);
            }
        }
    }
}

// ---------------------------------------------------------------------------
// own path part 1: hpart[kh][512][1536] = E_own @ W1 (K-half kh), raw sums
// ---------------------------------------------------------------------------
__global__ __launch_bounds__(256) void own_h(
        const float* __restrict__ E, const float* __restrict__ W1,
        float* __restrict__ hpart) {
    const int a   = blockIdx.x;
    const int col = blockIdx.y * 256 + threadIdx.x;
    const int kh  = blockIdx.z;
    const float* Erow = E + (size_t)(520 * a) * 768 + kh * 384;
    float acc[8] = {};
    for (int k = 0; k < 384; ++k) {
        const float w = W1[(size_t)(kh * 384 + k) * 1536 + col];
        #pragma unroll
        for (int j = 0; j < 8; ++j) acc[j] += w * Erow[(size_t)j * 768 + k];
    }
    #pragma unroll
    for (int j = 0; j < 8; ++j)
        hpart[(size_t)(kh * 512 + a * 8 + j) * 1536 + col] = acc[j];
}

// part 2: h = gelu_exact(p0+p1+b1), then fp32 LN -> hbuf (512 blocks)
__global__ __launch_bounds__(256) void own_ln(const float* __restrict__ hpart,
                                              const float* __restrict__ b1,
                                              const float* __restrict__ lng,
                                              const float* __restrict__ lnb,
                                              float* __restrict__ hbuf) {
    const int row = blockIdx.x, tid = threadIdx.x;
    const int lane = tid & 63, wv = tid >> 6;
    float x[6];
    #pragma unroll
    for (int i = 0; i < 6; ++i) {
        const int c = tid + i * 256;
        x[i] = gelu_exact(hpart[(size_t)row * 1536 + c]
                        + hpart[(size_t)(512 + row) * 1536 + c] + b1[c]);
    }
    __shared__ float red[8];
    float s = 0.f;
    #pragma unroll
    for (int i = 0; i < 6; ++i) s += x[i];
    #pragma unroll
    for (int o = 32; o > 0; o >>= 1) s += __shfl_xor(s, o, 64);
    if (lane == 0) red[wv] = s;
    __syncthreads();
    const float mu = (red[0] + red[1] + red[2] + red[3]) * (1.0f / 1536.0f);

    float s2 = 0.f;
    #pragma unroll
    for (int i = 0; i < 6; ++i) { float d = x[i] - mu; s2 += d * d; }
    #pragma unroll
    for (int o = 32; o > 0; o >>= 1) s2 += __shfl_xor(s2, o, 64);
    if (lane == 0) red[4 + wv] = s2;
    __syncthreads();
    const float rstd = rsqrtf((red[4] + red[5] + red[6] + red[7]) * (1.0f / 1536.0f) + 1e-12f);

    #pragma unroll
    for (int i = 0; i < 6; ++i) {
        const int c = tid + i * 256;
        hbuf[(size_t)row * 1536 + c] = (x[i] - mu) * rstd * lng[c] + lnb[c];
    }
}

// part 3: own[512][100] = hbuf @ W2 + b2, in-block K-split (d, ks) = (128, 2)
__global__ __launch_bounds__(256) void own_logits(
        const float* __restrict__ hbuf, const float* __restrict__ W2,
        const float* __restrict__ b2, float* __restrict__ own) {
    const int row = blockIdx.x;
    const int d  = threadIdx.x & 127;
    const int ks = threadIdx.x >> 7;
    const int dd = d < 100 ? d : 99;          // keep OOB lanes in-bounds
    const float* hr = hbuf + (size_t)row * 1536 + ks * 768;
    float acc = ks ? 0.0f : b2[dd];
    for (int k = 0; k < 768; ++k)
        acc += hr[k] * W2[(size_t)(ks * 768 + k) * 100 + dd];
    __shared__ float red[128];
    if (ks) red[d] = acc;
    __syncthreads();
    if (!ks && d < 100) own[(size_t)row * 100 + d] = acc + red[d];
}

// ---------------------------------------------------------------------------
// VG_scores / VG_index / sel  (fp32-exact argmax, first-max semantics)
// ---------------------------------------------------------------------------
__global__ __launch_bounds__(256) void finalize(const float* __restrict__ own,
                                                float* __restrict__ out,
                                                int* __restrict__ sel) {
    const int e = blockIdx.x * 256 + threadIdx.x;
    if (e >= 512) return;
    const float* r = own + (size_t)e * 100;
    float best = r[0]; int bi = 0;
    for (int i = 1; i < 100; ++i) {
        const float v = r[i];
        if (v > best) { best = v; bi = i; }
    }
    float s = 0.f;
    for (int i = 0; i < 100; ++i) s += expf(r[i] - best);
    out[262144 + e] = 1.0f / s;                   // VG_scores
    out[262656 + e] = (float)bi;                  // VG_scores_index
    if (e == 511) *sel = bi;
}

// gather W2 column sel (6 KB) + b2[sel]
__global__ __launch_bounds__(256) void w2gather(const float* __restrict__ W2,
                                                const float* __restrict__ b2,
                                                const int* __restrict__ selp,
                                                float* __restrict__ w2col,
                                                float* __restrict__ bsel) {
    const int t = blockIdx.x * 256 + threadIdx.x;   // 1536 threads
    const int sel = *selp;
    if (t < 1536) w2col[t] = W2[(size_t)t * 100 + sel];
    if (t == 0) bsel[0] = b2[sel];
}

// ---------------------------------------------------------------------------
// fused LayerNorm + GEMV: wave per row. out[row*8 .. row*8+7] =
//   dot(LN(act[row])*g + b, w2col) + bsel.  No logits buffer, no 2nd GEMM.
// ---------------------------------------------------------------------------
__global__ __launch_bounds__(256) void ln_gemv(
        const bf16_t* __restrict__ act, const float* __restrict__ lng,
        const float* __restrict__ lnb, const float* __restrict__ w2col,
        const float* __restrict__ bsel, float* __restrict__ out) {
    const int lane = threadIdx.x & 63, wv = threadIdx.x >> 6;
    const int row  = blockIdx.x * 4 + wv;
    const bf16_t* p = act + (size_t)row * 1536 + lane * 8;
    bf16x8 v[3];
    #pragma unroll
    for (int s = 0; s < 3; ++s) v[s] = *(const bf16x8*)(p + s * 512);
    float x[24];
    #pragma unroll
    for (int s = 0; s < 3; ++s)
        #pragma unroll
        for (int i = 0; i < 8; ++i) x[s * 8 + i] = (float)v[s][i];

    float sum = 0.f;
    #pragma unroll
    for (int i = 0; i < 24; ++i) sum += x[i];
    #pragma unroll
    for (int o = 32; o > 0; o >>= 1) sum += __shfl_xor(sum, o, 64);
    const float mu = sum * (1.0f / 1536.0f);

    float s2 = 0.f;
    #pragma unroll
    for (int i = 0; i < 24; ++i) { float d = x[i] - mu; s2 += d * d; }
    #pragma unroll
    for (int o = 32; o > 0; o >>= 1) s2 += __shfl_xor(s2, o, 64);
    const float rstd = rsqrtf(s2 * (1.0f / 1536.0f) + 1e-12f);

    float y = 0.f;
    #pragma unroll
    for (int s = 0; s < 3; ++s) {
        const int c = s * 512 + lane * 8;
        const float4 g0 = *(const float4*)(lng + c);
        const float4 g1 = *(const float4*)(lng + c + 4);
        const float4 b0 = *(const float4*)(lnb + c);
        const float4 b1 = *(const float4*)(lnb + c + 4);
        const float4 w0 = *(const float4*)(w2col + c);
        const float4 w1 = *(const float4*)(w2col + c + 4);
        const float gg[8] = {g0.x, g0.y, g0.z, g0.w, g1.x, g1.y, g1.z, g1.w};
        const float bb[8] = {b0.x, b0.y, b0.z, b0.w, b1.x, b1.y, b1.z, b1.w};
        const float ww[8] = {w0.x, w0.y, w0.z, w0.w, w1.x, w1.y, w1.z, w1.w};
        #pragma unroll
        for (int i = 0; i < 8; ++i)
            y += ((x[s * 8 + i] - mu) * rstd * gg[i] + bb[i]) * ww[i];
    }
    #pragma unroll
    for (int o = 32; o > 0; o >>= 1) y += __shfl_xor(y, o, 64);
    if (lane == 0) {
        const float vv = y + bsel[0];
        const float4 f = make_float4(vv, vv, vv, vv);
        float4* o = (float4*)(out + (size_t)row * 8);
        o[0] = f; o[1] = f;
    }
}

// ---------------------------------------------------------------------------
extern "C" void kernel_launch(void* const* d_in, const int* in_sizes, int n_in,
                              void* d_out, int out_size, void* d_ws, size_t ws_size,
                              hipStream_t stream) {
    const float* E   = (const float*)d_in[0];
    const float* W1  = (const float*)d_in[1];
    const float* b1  = (const float*)d_in[2];
    const float* lng = (const float*)d_in[3];
    const float* lnb = (const float*)d_in[4];
    const float* W2  = (const float*)d_in[5];
    const float* b2  = (const float*)d_in[6];
    float* out = (float*)d_out;

    char* w = (char*)d_ws;
    auto carve = [&](size_t bytes) {
        void* p = (void*)w;
        w += (bytes + 255) & ~(size_t)255;
        return p;
    };
    bf16_t* Ebf   = (bf16_t*)carve((size_t)25165824 * 2);     // 50.3 MB
    bf16_t* W1t   = (bf16_t*)carve((size_t)1536 * 768 * 2);   //  2.4 MB
    bf16_t* act   = (bf16_t*)carve((size_t)32768 * 1536 * 2); // 100.7 MB
    float*  hpart = (float*)carve((size_t)2 * 512 * 1536 * 4);//  6.3 MB
    float*  hbuf  = (float*)carve((size_t)512 * 1536 * 4);    //  3.1 MB
    float*  own   = (float*)carve((size_t)512 * 100 * 4);
    float*  w2col = (float*)carve(1536 * 4);
    float*  bsel  = (float*)carve(256);
    int*    sel   = (int*)carve(256);

    cvt_e<<<24576, 256, 0, stream>>>((const float4*)E, Ebf, 6291456);
    tr_w1<<<4608, 256, 0, stream>>>(W1, W1t);

    // GEMM1: -> act (gelu_fast, bf16), XCD-swizzled
    gemm1<<<dim3(12, 256), 256, 0, stream>>>(Ebf, W1t, b1, act);

    // exact fp32 own-row path -> sel
    own_h<<<dim3(64, 6, 2), 256, 0, stream>>>(E, W1, hpart);
    own_ln<<<512, 256, 0, stream>>>(hpart, b1, lng, lnb, hbuf);
    own_logits<<<512, 256, 0, stream>>>(hbuf, W2, b2, own);
    finalize<<<2, 256, 0, stream>>>(own, out, sel);
    w2gather<<<6, 256, 0, stream>>>(W2, b2, sel, w2col, bsel);

    // fused LN + GEMV over column sel -> output 0 directly
    ln_gemv<<<8192, 256, 0, stream>>>(act, lng, lnb, w2col, bsel, out);
}

// Round 7
// 378.930 us; speedup vs baseline: 1.3938x; 1.0165x over previous
//
#include <hip/hip_runtime.h>
#include <hip/hip_bf16.h>
#include <math.h>

// ---------------------------------------------------------------------------
// ModelFC_49134425866355 on MI355X (gfx950)
//
// Pipeline:
//   prep:   E fp32 -> bf16 ; W1 -> W1t bf16 [1536][768]
//   gemm1:  act = bf16( gelu_fast( E@W1 + b1 ) )  [32768][1536]  (MFMA)
//   own:    exact fp32 recompute of the 512 "own" rows (rows 520a+j):
//           own_h (LDS-staged E, float2 W1, k-split x4) -> own_ln (sum+gelu+LN)
//           -> own_logits -> finalize (argmax/softmax/sel + w2col gather fused)
//   lngemv: out[t*8+k] = dot(LN(act[t])*g+b, w2col) + bsel   (wave per row)
// ---------------------------------------------------------------------------

typedef __bf16 bf16_t;
typedef __bf16  bf16x8  __attribute__((ext_vector_type(8)));
typedef float   floatx4 __attribute__((ext_vector_type(4)));

__device__ __forceinline__ float gelu_exact(float x) {
    return 0.5f * x * (1.0f + erff(x * 0.7071067811865475f));
}
// tanh-form gelu via sigmoid; |err|<~1e-3, below bf16 rounding of bulk path.
__device__ __forceinline__ float gelu_fast(float x) {
    const float z = x * (1.0f + 0.044715f * x * x);
    return __fdividef(x, 1.0f + __expf(-1.5957691216f * z));
}

// async global->LDS, 16B per lane; lds base wave-uniform (HW adds lane*16).
// OFFSET ARG STAYS 0 — nonzero immediate is unverified and broke round 5.
__device__ __forceinline__ void gl_lds16(const bf16_t* g, bf16_t* l) {
    __builtin_amdgcn_global_load_lds(
        (const __attribute__((address_space(1))) void*)g,
        (__attribute__((address_space(3))) void*)l, 16, 0, 0);
}

// ---------------------------------------------------------------------------
// prep kernels
// ---------------------------------------------------------------------------
__global__ __launch_bounds__(256) void cvt_e(const float4* __restrict__ in,
                                             bf16_t* __restrict__ outp, int n4) {
    int t = blockIdx.x * 256 + threadIdx.x;
    if (t >= n4) return;
    float4 v = in[t];
    union { bf16_t h[4]; uint2 u; } u;
    u.h[0] = (bf16_t)v.x; u.h[1] = (bf16_t)v.y;
    u.h[2] = (bf16_t)v.z; u.h[3] = (bf16_t)v.w;
    *(uint2*)(outp + (size_t)t * 4) = u.u;
}

__global__ __launch_bounds__(256) void tr_w1(const float* __restrict__ W1,
                                             bf16_t* __restrict__ W1t) {
    int t = blockIdx.x * 256 + threadIdx.x;   // 1536*768 threads exactly
    int k = t % 768, n = t / 768;
    W1t[t] = (bf16_t)W1[(size_t)k * 1536 + n];
}

// ---------------------------------------------------------------------------
// GEMM1: [32768,768] @ [768,1536]^T-stored, 128x128 tile, BK=64, 12 K-tiles.
// ---------------------------------------------------------------------------
__global__ __launch_bounds__(256) void gemm1(
        const bf16_t* __restrict__ A, const bf16_t* __restrict__ Bt,
        const float* __restrict__ bias, bf16_t* __restrict__ C) {
    constexpr int K = 768, N = 1536;
    __shared__ alignas(16) bf16_t sA[128 * 64];   // 16 KB
    __shared__ alignas(16) bf16_t sB[128 * 64];   // 16 KB

    // XCD-aware remap: 12 n-tiles of one m-tile land on one XCD
    const int linear = blockIdx.x + gridDim.x * blockIdx.y;
    const int xcd  = linear & 7;
    const int slot = linear >> 3;
    const int bx = slot % gridDim.x;
    const int by = (slot / gridDim.x) * 8 + xcd;

    const int tid  = threadIdx.x;
    const int lane = tid & 63;
    const int wave = tid >> 6;
    const int wr = wave >> 1, wc = wave & 1;
    const int m0 = by * 128;
    const int n0 = bx * 128;
    const int q  = lane >> 4;
    const int l15 = lane & 15;

    // staging bases (computed once; swizzle gcol = col ^ (row&7) on source)
    const bf16_t* gA[4]; const bf16_t* gB[4];
    bf16_t* lA[4]; bf16_t* lB[4];
    #pragma unroll
    for (int c = 0; c < 4; ++c) {
        const int s    = c * 256 + tid;
        const int row  = s >> 3;             // 8 slots of 16B per 64-k row
        const int col  = s & 7;
        const int gcol = col ^ (row & 7);    // source-side swizzle
        gA[c] = A  + (size_t)(m0 + row) * K + gcol * 8;
        gB[c] = Bt + (size_t)(n0 + row) * K + gcol * 8;
        lA[c] = sA + (c * 256 + wave * 64) * 8;   // wave-uniform base
        lB[c] = sB + (c * 256 + wave * 64) * 8;
    }
    // LDS read bases (fixed across K-steps)
    const bf16_t* rA[4]; const bf16_t* rB[4];
    #pragma unroll
    for (int t4 = 0; t4 < 4; ++t4) {
        rA[t4] = sA + (wr * 64 + t4 * 16 + l15) * 64;
        rB[t4] = sB + (wc * 64 + t4 * 16 + l15) * 64;
    }
    const int c0 = ((q)     ^ (lane & 7)) * 8;   // rA row & 7 == lane & 7
    const int c1 = ((4 + q) ^ (lane & 7)) * 8;

    floatx4 acc[4][4] = {};

    #pragma unroll
    for (int kt = 0; kt < 12; ++kt) {
        const int k0 = kt * 64;
        __syncthreads();   // prev compute done before LDS overwrite
        #pragma unroll
        for (int c = 0; c < 4; ++c) {
            gl_lds16(gA[c] + k0, lA[c]);
            gl_lds16(gB[c] + k0, lB[c]);
        }
        __syncthreads();   // drain vmcnt then barrier

        #pragma unroll
        for (int ks = 0; ks < 2; ++ks) {
            const int co = ks ? c1 : c0;
            bf16x8 af[4], bfr[4];
            #pragma unroll
            for (int t4 = 0; t4 < 4; ++t4) {
                af[t4]  = *(const bf16x8*)(rA[t4] + co);
                bfr[t4] = *(const bf16x8*)(rB[t4] + co);
            }
            #pragma unroll
            for (int mt = 0; mt < 4; ++mt)
                #pragma unroll
                for (int nt = 0; nt < 4; ++nt)
                    acc[mt][nt] = __builtin_amdgcn_mfma_f32_16x16x32_bf16(
                        af[mt], bfr[nt], acc[mt][nt], 0, 0, 0);
        }
    }

    // epilogue: C/D layout col = lane&15, row = (lane>>4)*4 + r
    #pragma unroll
    for (int mt = 0; mt < 4; ++mt) {
        #pragma unroll
        for (int nt = 0; nt < 4; ++nt) {
            const int n = n0 + wc * 64 + nt * 16 + l15;
            const float bv = bias[n];
            #pragma unroll
            for (int r = 0; r < 4; ++r) {
                const int m = m0 + wr * 64 + mt * 16 + q * 4 + r;
                C[(size_t)m * N + n] = (bf16_t)gelu_fast(acc[mt][nt][r] + bv);
            }
        }
    }
}

// ---------------------------------------------------------------------------
// own path part 1: hpart[kq][512][1536] = E_own @ W1 (k-chunk kq of 4).
// E rows 520a..520a+7 are CONTIGUOUS -> LDS-staged once (coalesced); k-loop
// is 1 float2 W1 load + 8 LDS broadcasts (free) + 16 FMA per iteration.
// grid (64, 3, 4) = 768 blocks, 256 thr; thread owns cols {c0, c0+1} x 8 rows.
// ---------------------------------------------------------------------------
__global__ __launch_bounds__(256) void own_h(
        const float* __restrict__ E, const float* __restrict__ W1,
        float* __restrict__ hpart) {
    const int a  = blockIdx.x;          // 0..63
    const int by = blockIdx.y;          // 0..2  (512 cols each)
    const int kq = blockIdx.z;          // 0..3  (192 k each)
    const int tid = threadIdx.x;
    __shared__ float sE[8 * 192];       // 6 KB

    const float* Ebase = E + (size_t)(520 * a) * 768 + kq * 192;
    #pragma unroll
    for (int idx = tid; idx < 1536; idx += 256) {
        const int row = idx / 192, i = idx - row * 192;
        sE[idx] = Ebase[(size_t)row * 768 + i];
    }
    __syncthreads();

    const int c0 = by * 512 + tid * 2;
    const float* w1p = W1 + (size_t)(kq * 192) * 1536 + c0;
    float ax[8] = {}, ay[8] = {};
    for (int k = 0; k < 192; ++k) {
        const float2 w = *(const float2*)(w1p + (size_t)k * 1536);
        #pragma unroll
        for (int j = 0; j < 8; ++j) {
            const float e = sE[j * 192 + k];   // LDS broadcast
            ax[j] += w.x * e;
            ay[j] += w.y * e;
        }
    }
    #pragma unroll
    for (int j = 0; j < 8; ++j)
        *(float2*)(hpart + (size_t)(kq * 512 + a * 8 + j) * 1536 + c0)
            = make_float2(ax[j], ay[j]);
}

// part 2: h = gelu_exact(p0+p1+p2+p3+b1), then fp32 LN -> hbuf (512 blocks)
__global__ __launch_bounds__(256) void own_ln(const float* __restrict__ hpart,
                                              const float* __restrict__ b1,
                                              const float* __restrict__ lng,
                                              const float* __restrict__ lnb,
                                              float* __restrict__ hbuf) {
    const int row = blockIdx.x, tid = threadIdx.x;
    const int lane = tid & 63, wv = tid >> 6;
    float x[6];
    #pragma unroll
    for (int i = 0; i < 6; ++i) {
        const int c = tid + i * 256;
        x[i] = gelu_exact(hpart[(size_t)row * 1536 + c]
                        + hpart[(size_t)(512 + row) * 1536 + c]
                        + hpart[(size_t)(1024 + row) * 1536 + c]
                        + hpart[(size_t)(1536 + row) * 1536 + c] + b1[c]);
    }
    __shared__ float red[8];
    float s = 0.f;
    #pragma unroll
    for (int i = 0; i < 6; ++i) s += x[i];
    #pragma unroll
    for (int o = 32; o > 0; o >>= 1) s += __shfl_xor(s, o, 64);
    if (lane == 0) red[wv] = s;
    __syncthreads();
    const float mu = (red[0] + red[1] + red[2] + red[3]) * (1.0f / 1536.0f);

    float s2 = 0.f;
    #pragma unroll
    for (int i = 0; i < 6; ++i) { float d = x[i] - mu; s2 += d * d; }
    #pragma unroll
    for (int o = 32; o > 0; o >>= 1) s2 += __shfl_xor(s2, o, 64);
    if (lane == 0) red[4 + wv] = s2;
    __syncthreads();
    const float rstd = rsqrtf((red[4] + red[5] + red[6] + red[7]) * (1.0f / 1536.0f) + 1e-12f);

    #pragma unroll
    for (int i = 0; i < 6; ++i) {
        const int c = tid + i * 256;
        hbuf[(size_t)row * 1536 + c] = (x[i] - mu) * rstd * lng[c] + lnb[c];
    }
}

// part 3: own[512][100] = hbuf @ W2 + b2, in-block K-split (d, ks) = (128, 2)
__global__ __launch_bounds__(256) void own_logits(
        const float* __restrict__ hbuf, const float* __restrict__ W2,
        const float* __restrict__ b2, float* __restrict__ own) {
    const int row = blockIdx.x;
    const int d  = threadIdx.x & 127;
    const int ks = threadIdx.x >> 7;
    const int dd = d < 100 ? d : 99;          // keep OOB lanes in-bounds
    const float* hr = hbuf + (size_t)row * 1536 + ks * 768;
    float acc = ks ? 0.0f : b2[dd];
    for (int k = 0; k < 768; ++k)
        acc += hr[k] * W2[(size_t)(ks * 768 + k) * 100 + dd];
    __shared__ float red[128];
    if (ks) red[d] = acc;
    __syncthreads();
    if (!ks && d < 100) own[(size_t)row * 100 + d] = acc + red[d];
}

// ---------------------------------------------------------------------------
// finalize: VG_scores / VG_index (fp32-exact, first-max) + fused w2col gather.
// ONE block of 512 threads; sel crosses via LDS.
// ---------------------------------------------------------------------------
__global__ __launch_bounds__(512) void finalize(const float* __restrict__ own,
                                                const float* __restrict__ W2,
                                                const float* __restrict__ b2,
                                                float* __restrict__ out,
                                                float* __restrict__ w2col,
                                                float* __restrict__ bsel) {
    __shared__ int ssel;
    const int e = threadIdx.x;                    // 0..511
    const float* r = own + (size_t)e * 100;
    float best = r[0]; int bi = 0;
    for (int i = 1; i < 100; ++i) {
        const float v = r[i];
        if (v > best) { best = v; bi = i; }       // strict > keeps first max
    }
    float s = 0.f;
    for (int i = 0; i < 100; ++i) s += expf(r[i] - best);
    out[262144 + e] = 1.0f / s;                   // VG_scores
    out[262656 + e] = (float)bi;                  // VG_scores_index
    if (e == 511) ssel = bi;
    __syncthreads();
    const int sel = ssel;
    #pragma unroll
    for (int t = e; t < 1536; t += 512) w2col[t] = W2[(size_t)t * 100 + sel];
    if (e == 0) bsel[0] = b2[sel];
}

// ---------------------------------------------------------------------------
// fused LayerNorm + GEMV: wave per row. out[row*8 .. row*8+7] =
//   dot(LN(act[row])*g + b, w2col) + bsel.
// ---------------------------------------------------------------------------
__global__ __launch_bounds__(256) void ln_gemv(
        const bf16_t* __restrict__ act, const float* __restrict__ lng,
        const float* __restrict__ lnb, const float* __restrict__ w2col,
        const float* __restrict__ bsel, float* __restrict__ out) {
    const int lane = threadIdx.x & 63, wv = threadIdx.x >> 6;
    const int row  = blockIdx.x * 4 + wv;
    const bf16_t* p = act + (size_t)row * 1536 + lane * 8;
    bf16x8 v[3];
    #pragma unroll
    for (int s = 0; s < 3; ++s) v[s] = *(const bf16x8*)(p + s * 512);
    float x[24];
    #pragma unroll
    for (int s = 0; s < 3; ++s)
        #pragma unroll
        for (int i = 0; i < 8; ++i) x[s * 8 + i] = (float)v[s][i];

    float sum = 0.f;
    #pragma unroll
    for (int i = 0; i < 24; ++i) sum += x[i];
    #pragma unroll
    for (int o = 32; o > 0; o >>= 1) sum += __shfl_xor(sum, o, 64);
    const float mu = sum * (1.0f / 1536.0f);

    float s2 = 0.f;
    #pragma unroll
    for (int i = 0; i < 24; ++i) { float d = x[i] - mu; s2 += d * d; }
    #pragma unroll
    for (int o = 32; o > 0; o >>= 1) s2 += __shfl_xor(s2, o, 64);
    const float rstd = rsqrtf(s2 * (1.0f / 1536.0f) + 1e-12f);

    float y = 0.f;
    #pragma unroll
    for (int s = 0; s < 3; ++s) {
        const int c = s * 512 + lane * 8;
        const float4 g0 = *(const float4*)(lng + c);
        const float4 g1 = *(const float4*)(lng + c + 4);
        const float4 b0 = *(const float4*)(lnb + c);
        const float4 b1 = *(const float4*)(lnb + c + 4);
        const float4 w0 = *(const float4*)(w2col + c);
        const float4 w1 = *(const float4*)(w2col + c + 4);
        const float gg[8] = {g0.x, g0.y, g0.z, g0.w, g1.x, g1.y, g1.z, g1.w};
        const float bb[8] = {b0.x, b0.y, b0.z, b0.w, b1.x, b1.y, b1.z, b1.w};
        const float ww[8] = {w0.x, w0.y, w0.z, w0.w, w1.x, w1.y, w1.z, w1.w};
        #pragma unroll
        for (int i = 0; i < 8; ++i)
            y += ((x[s * 8 + i] - mu) * rstd * gg[i] + bb[i]) * ww[i];
    }
    #pragma unroll
    for (int o = 32; o > 0; o >>= 1) y += __shfl_xor(y, o, 64);
    if (lane == 0) {
        const float vv = y + bsel[0];
        const float4 f = make_float4(vv, vv, vv, vv);
        float4* o = (float4*)(out + (size_t)row * 8);
        o[0] = f; o[1] = f;
    }
}

// ---------------------------------------------------------------------------
extern "C" void kernel_launch(void* const* d_in, const int* in_sizes, int n_in,
                              void* d_out, int out_size, void* d_ws, size_t ws_size,
                              hipStream_t stream) {
    const float* E   = (const float*)d_in[0];
    const float* W1  = (const float*)d_in[1];
    const float* b1  = (const float*)d_in[2];
    const float* lng = (const float*)d_in[3];
    const float* lnb = (const float*)d_in[4];
    const float* W2  = (const float*)d_in[5];
    const float* b2  = (const float*)d_in[6];
    float* out = (float*)d_out;

    char* w = (char*)d_ws;
    auto carve = [&](size_t bytes) {
        void* p = (void*)w;
        w += (bytes + 255) & ~(size_t)255;
        return p;
    };
    bf16_t* Ebf   = (bf16_t*)carve((size_t)25165824 * 2);     // 50.3 MB
    bf16_t* W1t   = (bf16_t*)carve((size_t)1536 * 768 * 2);   //  2.4 MB
    bf16_t* act   = (bf16_t*)carve((size_t)32768 * 1536 * 2); // 100.7 MB
    float*  hpart = (float*)carve((size_t)4 * 512 * 1536 * 4);// 12.6 MB
    float*  hbuf  = (float*)carve((size_t)512 * 1536 * 4);    //  3.1 MB
    float*  own   = (float*)carve((size_t)512 * 100 * 4);
    float*  w2col = (float*)carve(1536 * 4);
    float*  bsel  = (float*)carve(256);

    cvt_e<<<24576, 256, 0, stream>>>((const float4*)E, Ebf, 6291456);
    tr_w1<<<4608, 256, 0, stream>>>(W1, W1t);

    // GEMM1: -> act (gelu_fast, bf16), XCD-swizzled
    gemm1<<<dim3(12, 256), 256, 0, stream>>>(Ebf, W1t, b1, act);

    // exact fp32 own-row path -> w2col/bsel
    own_h<<<dim3(64, 3, 4), 256, 0, stream>>>(E, W1, hpart);
    own_ln<<<512, 256, 0, stream>>>(hpart, b1, lng, lnb, hbuf);
    own_logits<<<512, 256, 0, stream>>>(hbuf, W2, b2, own);
    finalize<<<1, 512, 0, stream>>>(own, W2, b2, out, w2col, bsel);

    // fused LN + GEMV over column sel -> output 0 directly
    ln_gemv<<<8192, 256, 0, stream>>>(act, lng, lnb, w2col, bsel, out);
}